// Round 11
// baseline (366.885 us; speedup 1.0000x reference)
//
#include <hip/hip_runtime.h>

// SpikeFFN: out = spike(LIF(x @ W1^T)) @ W2^T ; T=4 B=8 N=1024 C=512, fp32.
//
// HARD CONSTRAINT (r8): GEMM1 = single full-K ascending serial FMA chain per
// output in fp32 (np reference arithmetic); v_fma_f32 == CPU vfmadd.
// Tiling/load order free; per-output chain order is not.
//
// r10 post-mortem: 8x16/thread still LDS-bound (6 b128 per 128 FMA; LDS 576
// vs VALU 512 cyc per CU-k). r11: 16x16/thread, 256x256 tile, 1 block/CU:
// 8 b128 per 256 FMA -> LDS 384 < VALU 512 cyc (VALU-bound, 25% headroom).
// Double-buffered LDS (142 KB) + register prefetch, one barrier per k-tile.

typedef _Float16 half8  __attribute__((ext_vector_type(8)));
typedef _Float16 half4v __attribute__((ext_vector_type(4)));
typedef float    f32x4  __attribute__((ext_vector_type(4)));

constexpr int TT   = 4;
constexpr int BB   = 8;
constexpr int NN   = 1024;
constexpr int CC   = 512;                 // Cin == Cout
constexpr int MROW = BB * NN;             // 8192 rows per timestep
constexpr int MTOT = TT * MROW;           // 32768 rows total
constexpr int BNC  = MROW * CC;           // per-timestep elems
constexpr int LDK  = 40;                  // fp16 LDS stride (gemm2)
constexpr int LTA3 = 284;                 // PADI(255)+1, multiple of 4

__device__ __forceinline__ int PADI(int r) { return r + ((r >> 5) << 2); }

// ---------- GEMM1: single full-K ascending serial FMA chain (fp32) ---------
// 256x256 block tile, 256 threads, 16x16 outputs/thread, BK=32, dbuf LDS.
__global__ __launch_bounds__(256, 1)
void gemm1_chain4(const float* __restrict__ X, const float* __restrict__ W,
                  float* __restrict__ H) {
#pragma clang fp contract(off)
    __shared__ float At[2][32][LTA3];   // 71 KB
    __shared__ float Bt[2][32][LTA3];   // 71 KB   (total 142 KB)

    const int tid = threadIdx.x;
    const int RM  = blockIdx.x * 256;
    const int CN  = blockIdx.y * 256;
    const int tx  = tid & 15;            // col group (16 cols)
    const int ty  = tid >> 4;            // row group (16 rows)
    const int abase = PADI(ty * 16);     // contiguous 16 (pads at 32-boundaries)
    const int bbase = PADI(tx * 16);
    const int rot = tid & 3;

    const int srow = tid >> 3;           // base staging row (row = srow + 32j)
    const int sc4  = (tid & 7) * 4;      // staging k-quad
    const int spr0 = PADI(srow);         // PADI(srow+32j) = spr0 + 36j

    float acc[16][16] = {};              // ONE accumulator per output (256 VGPR)
    f32x4 ra[8], rb[8];

    // prologue: load tile 0, write buf 0, load tile 1
#pragma unroll
    for (int j = 0; j < 8; ++j) {
        size_t ro = (size_t)(RM + srow + 32 * j) * CC + sc4;
        size_t co = (size_t)(CN + srow + 32 * j) * CC + sc4;
        ra[j] = *(const f32x4*)&X[ro];
        rb[j] = *(const f32x4*)&W[co];
    }
#pragma unroll
    for (int j = 0; j < 8; ++j) {
        int pr = spr0 + 36 * j;
#pragma unroll
        for (int e = 0; e < 4; ++e) {
            int ee = (e + rot) & 3;
            At[0][sc4 + ee][pr] = ra[j][ee];
            Bt[0][sc4 + ee][pr] = rb[j][ee];
        }
    }
#pragma unroll
    for (int j = 0; j < 8; ++j) {
        size_t ro = (size_t)(RM + srow + 32 * j) * CC + 32 + sc4;
        size_t co = (size_t)(CN + srow + 32 * j) * CC + 32 + sc4;
        ra[j] = *(const f32x4*)&X[ro];
        rb[j] = *(const f32x4*)&W[co];
    }
    __syncthreads();

    for (int kt = 0; kt < 16; ++kt) {
        const int cur = kt & 1;
        // write tile kt+1 (already in regs, landed during previous FMA phase)
        if (kt < 15) {
#pragma unroll
            for (int j = 0; j < 8; ++j) {
                int pr = spr0 + 36 * j;
#pragma unroll
                for (int e = 0; e < 4; ++e) {
                    int ee = (e + rot) & 3;
                    At[cur ^ 1][sc4 + ee][pr] = ra[j][ee];
                    Bt[cur ^ 1][sc4 + ee][pr] = rb[j][ee];
                }
            }
        }
        // issue loads for tile kt+2
        if (kt < 14) {
            int kk = (kt + 2) * 32;
#pragma unroll
            for (int j = 0; j < 8; ++j) {
                size_t ro = (size_t)(RM + srow + 32 * j) * CC + kk + sc4;
                size_t co = (size_t)(CN + srow + 32 * j) * CC + kk + sc4;
                ra[j] = *(const f32x4*)&X[ro];
                rb[j] = *(const f32x4*)&W[co];
            }
        }
        // FMA phase on buf[cur], strict ascending k
        const float (*Ac)[LTA3] = At[cur];
        const float (*Bc)[LTA3] = Bt[cur];
#pragma unroll 1
        for (int k = 0; k < 32; ++k) {
            f32x4 a0 = *(const f32x4*)&Ac[k][abase];
            f32x4 a1 = *(const f32x4*)&Ac[k][abase + 4];
            f32x4 a2 = *(const f32x4*)&Ac[k][abase + 8];
            f32x4 a3 = *(const f32x4*)&Ac[k][abase + 12];
            f32x4 b0 = *(const f32x4*)&Bc[k][bbase];
            f32x4 b1 = *(const f32x4*)&Bc[k][bbase + 4];
            f32x4 b2 = *(const f32x4*)&Bc[k][bbase + 8];
            f32x4 b3 = *(const f32x4*)&Bc[k][bbase + 12];
            float a[16] = {a0[0], a0[1], a0[2], a0[3], a1[0], a1[1], a1[2], a1[3],
                           a2[0], a2[1], a2[2], a2[3], a3[0], a3[1], a3[2], a3[3]};
            float b[16] = {b0[0], b0[1], b0[2], b0[3], b1[0], b1[1], b1[2], b1[3],
                           b2[0], b2[1], b2[2], b2[3], b3[0], b3[1], b3[2], b3[3]};
#pragma unroll
            for (int i = 0; i < 16; ++i)
#pragma unroll
                for (int jj = 0; jj < 16; ++jj)
                    acc[i][jj] = __builtin_fmaf(a[i], b[jj], acc[i][jj]);
        }
        __syncthreads();
    }

#pragma unroll
    for (int i = 0; i < 16; ++i) {
        size_t base = (size_t)(RM + ty * 16 + i) * CC + CN + tx * 16;
#pragma unroll
        for (int q = 0; q < 4; ++q) {
            f32x4 o = {acc[i][q * 4], acc[i][q * 4 + 1],
                       acc[i][q * 4 + 2], acc[i][q * 4 + 3]};
            *(f32x4*)&H[base + q * 4] = o;
        }
    }
}

// ----------------------------- LIF (fp32, np-op-exact) ---------------------
__global__ __launch_bounds__(256)
void lif_np(const float* __restrict__ H, _Float16* __restrict__ S) {
#pragma clang fp contract(off)
    int g = blockIdx.x * 256 + threadIdx.x;   // 0 .. BNC/4-1
    float v[4] = {0.f, 0.f, 0.f, 0.f};
#pragma unroll
    for (int t = 0; t < TT; ++t) {
        f32x4 h = *(const f32x4*)&H[(size_t)t * BNC + (size_t)g * 4];
        half4v s;
#pragma unroll
        for (int e = 0; e < 4; ++e) {
            float d  = h[e] - v[e];          // rounded sub (np: x - (v-0))
            float d2 = d * 0.5f;             // exact (np: /2.0)
            v[e] = v[e] + d2;                // rounded add
            bool sp = v[e] >= 1.0f;
            s[e] = sp ? (_Float16)1.0f : (_Float16)0.0f;
            if (sp) v[e] = 0.0f;             // hard reset (np: v*(1-s)+0*s)
        }
        *(half4v*)&S[(size_t)t * BNC + (size_t)g * 4] = s;
    }
}

// ---------------------------------------------------------------- GEMM2 ----
// O[m][p] = sum_o S[m][o] * W2[p][o]. fp16 MFMA; spikes exact in fp16.
__global__ __launch_bounds__(256)
void gemm2_f16(const _Float16* __restrict__ S, const float* __restrict__ W,
               float* __restrict__ O) {
    __shared__ _Float16 As[128][LDK], Bs[128][LDK];

    const int tid  = threadIdx.x;
    const int RM   = blockIdx.x * 128;
    const int CN   = blockIdx.y * 128;
    const int lane = tid & 63;
    const int wv   = tid >> 6;
    const int wr   = (wv >> 1) * 64;
    const int wc   = (wv & 1) * 64;
    const int r15  = lane & 15;
    const int kg   = lane >> 4;

    f32x4 acc[4][4] = {};

    for (int k0 = 0; k0 < CC; k0 += 32) {
        __syncthreads();
#pragma unroll
        for (int j = 0; j < 2; ++j) {
            int id  = tid + 256 * j;
            int row = id >> 2;
            int c8  = (id & 3) * 8;
            *(half8*)&As[row][c8] =
                *(const half8*)&S[(size_t)(RM + row) * CC + k0 + c8];
        }
#pragma unroll
        for (int j = 0; j < 4; ++j) {
            int id  = tid + 256 * j;
            int row = id >> 3;
            int c4  = (id & 7) * 4;
            f32x4 v = *(const f32x4*)&W[(size_t)(CN + row) * CC + k0 + c4];
            half4v hv;
#pragma unroll
            for (int e = 0; e < 4; ++e) hv[e] = (_Float16)v[e];
            *(half4v*)&Bs[row][c4] = hv;
        }
        __syncthreads();

        half8 a[4], b[4];
#pragma unroll
        for (int i = 0; i < 4; ++i) {
            a[i] = *(const half8*)&As[wr + i * 16 + r15][kg * 8];
            b[i] = *(const half8*)&Bs[wc + i * 16 + r15][kg * 8];
        }
#pragma unroll
        for (int i = 0; i < 4; ++i)
#pragma unroll
            for (int j = 0; j < 4; ++j)
                acc[i][j] = __builtin_amdgcn_mfma_f32_16x16x32_f16(a[i], b[j], acc[i][j], 0, 0, 0);
    }

#pragma unroll
    for (int i = 0; i < 4; ++i)
#pragma unroll
        for (int j = 0; j < 4; ++j)
#pragma unroll
            for (int r = 0; r < 4; ++r) {
                int gm = RM + wr + i * 16 + kg * 4 + r;
                int gn = CN + wc + j * 16 + r15;
                O[(size_t)gm * CC + gn] = acc[i][j][r];
            }
}

// -------------------------------------------------------------- launch -----
extern "C" void kernel_launch(void* const* d_in, const int* in_sizes, int n_in,
                              void* d_out, int out_size, void* d_ws, size_t ws_size,
                              hipStream_t stream) {
    const float* x  = (const float*)d_in[0];
    const float* W1 = (const float*)d_in[1];
    const float* W2 = (const float*)d_in[2];
    float* out = (float*)d_out;

    float*    h = out;               // fp32 h in d_out (clobbered by GEMM2)
    _Float16* s = (_Float16*)d_ws;   // fp16 spikes, 32 MB

    dim3 g1(MTOT / 256, CC / 256);   // (128, 2) = 256 blocks = 1/CU exactly
    gemm1_chain4<<<g1, 256, 0, stream>>>(x, W1, h);

    lif_np<<<BNC / 4 / 256, 256, 0, stream>>>(h, s);

    dim3 g2(MTOT / 128, CC / 128);   // (256, 4)
    gemm2_f16<<<g2, 256, 0, stream>>>(s, W2, out);
}

// Round 12
// 280.577 us; speedup vs baseline: 1.3076x; 1.3076x over previous
//
#include <hip/hip_runtime.h>

// SpikeFFN: out = spike(LIF(x @ W1^T)) @ W2^T ; T=4 B=8 N=1024 C=512, fp32.
//
// HARD CONSTRAINT (r8): GEMM1 = single full-K ascending serial FMA chain per
// output in fp32 (np reference arithmetic); v_fma_f32 == CPU vfmadd.
// Tiling/load order free; per-output chain order is not.
//
// r11 post-mortem: 16x16/thread spilled (VGPR_Count 208 < 256 accs) -> 366us.
// r12: back to r10's proven 128x256 geometry (8x16/thread, 54KB LDS,
// 2 blocks/CU) + register prefetch (T14 async-split): global loads for tile
// kt+1 are issued BEFORE kt's FMA phase and land under it; the staging phase
// between barriers is only 48 scalar LDS writes. This removes the ~600cyc
// HBM latency r10 exposed on every one of its 16 k-tiles (~25% of runtime).

typedef _Float16 half8  __attribute__((ext_vector_type(8)));
typedef _Float16 half4v __attribute__((ext_vector_type(4)));
typedef float    f32x4  __attribute__((ext_vector_type(4)));

constexpr int TT   = 4;
constexpr int BB   = 8;
constexpr int NN   = 1024;
constexpr int CC   = 512;                 // Cin == Cout
constexpr int MROW = BB * NN;             // 8192 rows per timestep
constexpr int MTOT = TT * MROW;           // 32768 rows total
constexpr int BNC  = MROW * CC;           // per-timestep elems
constexpr int LDK  = 40;                  // fp16 LDS stride (gemm2)
constexpr int LTA  = 140;                 // PADI(127)+1 (mult of 4)
constexpr int LTB  = 284;                 // PADI(255)+1 (mult of 4)

__device__ __forceinline__ int PADI(int r) { return r + ((r >> 5) << 2); }

// ---------- GEMM1: single full-K ascending serial FMA chain (fp32) ---------
// 128x256 block tile, 256 threads, 8 rows x 16 cols per thread, BK=32.
// Single LDS buffer (54 KB, 2 blocks/CU); next tile prefetched in registers.
__global__ __launch_bounds__(256, 2)
void gemm1_chain5(const float* __restrict__ X, const float* __restrict__ W,
                  float* __restrict__ H) {
#pragma clang fp contract(off)
    __shared__ float At[32][LTA];   // [k][P(m)] 17.9 KB
    __shared__ float Bt[32][LTB];   // [k][P(o)] 36.4 KB

    const int tid = threadIdx.x;
    const int RM  = blockIdx.x * 128;
    const int CN  = blockIdx.y * 256;
    const int tx  = tid & 15;            // col group (16 cols)
    const int ty  = tid >> 4;            // row group (8 rows)
    const int abase = PADI(ty * 8);      // contiguous 8 (no pad inside)
    const int bbase = PADI(tx * 16);     // contiguous 16 (no pad inside)
    const int rot   = tid & 3;           // staging-write rotation

    // staging decomposition: thread covers 4 A-quads and 8 B-quads per tile
    const int arow = tid >> 3;           // A row 0..31 (+32j)
    const int ac4  = (tid & 7) * 4;      // A k-quad
    const int brow = tid >> 3;           // B row 0..31 (+32j)
    const int bc4  = (tid & 7) * 4;

    float acc[8][16] = {};               // ONE accumulator per output
    f32x4 ra[4], rb[8];                  // prefetch registers (48 VGPR)

    // ---- prologue: load tile 0, stage it, issue loads for tile 1 ----
#pragma unroll
    for (int j = 0; j < 4; ++j)
        ra[j] = *(const f32x4*)&X[(size_t)(RM + arow + 32 * j) * CC + ac4];
#pragma unroll
    for (int j = 0; j < 8; ++j)
        rb[j] = *(const f32x4*)&W[(size_t)(CN + brow + 32 * j) * CC + bc4];

#pragma unroll
    for (int j = 0; j < 4; ++j) {
        int pr = PADI(arow + 32 * j);
#pragma unroll
        for (int e = 0; e < 4; ++e) {
            int ee = (e + rot) & 3;
            At[ac4 + ee][pr] = ra[j][ee];
        }
    }
#pragma unroll
    for (int j = 0; j < 8; ++j) {
        int pr = PADI(brow + 32 * j);
#pragma unroll
        for (int e = 0; e < 4; ++e) {
            int ee = (e + rot) & 3;
            Bt[bc4 + ee][pr] = rb[j][ee];
        }
    }
    // issue loads for tile 1 (consumed at next staging)
#pragma unroll
    for (int j = 0; j < 4; ++j)
        ra[j] = *(const f32x4*)&X[(size_t)(RM + arow + 32 * j) * CC + 32 + ac4];
#pragma unroll
    for (int j = 0; j < 8; ++j)
        rb[j] = *(const f32x4*)&W[(size_t)(CN + brow + 32 * j) * CC + 32 + bc4];
    __syncthreads();

    for (int kt = 0; kt < 16; ++kt) {
        // ---- FMA phase on current buffer, strict ascending k ----
#pragma unroll 2
        for (int k = 0; k < 32; ++k) {
            f32x4 a0 = *(const f32x4*)&At[k][abase];
            f32x4 a1 = *(const f32x4*)&At[k][abase + 4];
            f32x4 b0 = *(const f32x4*)&Bt[k][bbase];
            f32x4 b1 = *(const f32x4*)&Bt[k][bbase + 4];
            f32x4 b2 = *(const f32x4*)&Bt[k][bbase + 8];
            f32x4 b3 = *(const f32x4*)&Bt[k][bbase + 12];
            float a[8]  = {a0[0], a0[1], a0[2], a0[3], a1[0], a1[1], a1[2], a1[3]};
            float b[16] = {b0[0], b0[1], b0[2], b0[3], b1[0], b1[1], b1[2], b1[3],
                           b2[0], b2[1], b2[2], b2[3], b3[0], b3[1], b3[2], b3[3]};
#pragma unroll
            for (int i = 0; i < 8; ++i)
#pragma unroll
                for (int jj = 0; jj < 16; ++jj)
                    acc[i][jj] = __builtin_fmaf(a[i], b[jj], acc[i][jj]);
        }

        if (kt < 15) {
            __syncthreads();   // everyone done reading the buffer
            // stage tile kt+1 from prefetch regs (fast: 48 scalar writes)
#pragma unroll
            for (int j = 0; j < 4; ++j) {
                int pr = PADI(arow + 32 * j);
#pragma unroll
                for (int e = 0; e < 4; ++e) {
                    int ee = (e + rot) & 3;
                    At[ac4 + ee][pr] = ra[j][ee];
                }
            }
#pragma unroll
            for (int j = 0; j < 8; ++j) {
                int pr = PADI(brow + 32 * j);
#pragma unroll
                for (int e = 0; e < 4; ++e) {
                    int ee = (e + rot) & 3;
                    Bt[bc4 + ee][pr] = rb[j][ee];
                }
            }
            // issue loads for tile kt+2 (land during kt+1's FMA phase)
            if (kt < 14) {
                int kk = (kt + 2) * 32;
#pragma unroll
                for (int j = 0; j < 4; ++j)
                    ra[j] = *(const f32x4*)&X[(size_t)(RM + arow + 32 * j) * CC + kk + ac4];
#pragma unroll
                for (int j = 0; j < 8; ++j)
                    rb[j] = *(const f32x4*)&W[(size_t)(CN + brow + 32 * j) * CC + kk + bc4];
            }
            __syncthreads();   // staged data visible
        }
    }

#pragma unroll
    for (int i = 0; i < 8; ++i) {
        size_t base = (size_t)(RM + ty * 8 + i) * CC + CN + tx * 16;
#pragma unroll
        for (int q = 0; q < 4; ++q) {
            f32x4 o = {acc[i][q * 4], acc[i][q * 4 + 1],
                       acc[i][q * 4 + 2], acc[i][q * 4 + 3]};
            *(f32x4*)&H[base + q * 4] = o;
        }
    }
}

// ----------------------------- LIF (fp32, np-op-exact) ---------------------
__global__ __launch_bounds__(256)
void lif_np(const float* __restrict__ H, _Float16* __restrict__ S) {
#pragma clang fp contract(off)
    int g = blockIdx.x * 256 + threadIdx.x;   // 0 .. BNC/4-1
    float v[4] = {0.f, 0.f, 0.f, 0.f};
#pragma unroll
    for (int t = 0; t < TT; ++t) {
        f32x4 h = *(const f32x4*)&H[(size_t)t * BNC + (size_t)g * 4];
        half4v s;
#pragma unroll
        for (int e = 0; e < 4; ++e) {
            float d  = h[e] - v[e];          // rounded sub (np: x - (v-0))
            float d2 = d * 0.5f;             // exact (np: /2.0)
            v[e] = v[e] + d2;                // rounded add
            bool sp = v[e] >= 1.0f;
            s[e] = sp ? (_Float16)1.0f : (_Float16)0.0f;
            if (sp) v[e] = 0.0f;             // hard reset (np: v*(1-s)+0*s)
        }
        *(half4v*)&S[(size_t)t * BNC + (size_t)g * 4] = s;
    }
}

// ---------------------------------------------------------------- GEMM2 ----
// O[m][p] = sum_o S[m][o] * W2[p][o]. fp16 MFMA; spikes exact in fp16.
__global__ __launch_bounds__(256)
void gemm2_f16(const _Float16* __restrict__ S, const float* __restrict__ W,
               float* __restrict__ O) {
    __shared__ _Float16 As[128][LDK], Bs[128][LDK];

    const int tid  = threadIdx.x;
    const int RM   = blockIdx.x * 128;
    const int CN   = blockIdx.y * 128;
    const int lane = tid & 63;
    const int wv   = tid >> 6;
    const int wr   = (wv >> 1) * 64;
    const int wc   = (wv & 1) * 64;
    const int r15  = lane & 15;
    const int kg   = lane >> 4;

    f32x4 acc[4][4] = {};

    for (int k0 = 0; k0 < CC; k0 += 32) {
        __syncthreads();
#pragma unroll
        for (int j = 0; j < 2; ++j) {
            int id  = tid + 256 * j;
            int row = id >> 2;
            int c8  = (id & 3) * 8;
            *(half8*)&As[row][c8] =
                *(const half8*)&S[(size_t)(RM + row) * CC + k0 + c8];
        }
#pragma unroll
        for (int j = 0; j < 4; ++j) {
            int id  = tid + 256 * j;
            int row = id >> 3;
            int c4  = (id & 7) * 4;
            f32x4 v = *(const f32x4*)&W[(size_t)(CN + row) * CC + k0 + c4];
            half4v hv;
#pragma unroll
            for (int e = 0; e < 4; ++e) hv[e] = (_Float16)v[e];
            *(half4v*)&Bs[row][c4] = hv;
        }
        __syncthreads();

        half8 a[4], b[4];
#pragma unroll
        for (int i = 0; i < 4; ++i) {
            a[i] = *(const half8*)&As[wr + i * 16 + r15][kg * 8];
            b[i] = *(const half8*)&Bs[wc + i * 16 + r15][kg * 8];
        }
#pragma unroll
        for (int i = 0; i < 4; ++i)
#pragma unroll
            for (int j = 0; j < 4; ++j)
                acc[i][j] = __builtin_amdgcn_mfma_f32_16x16x32_f16(a[i], b[j], acc[i][j], 0, 0, 0);
    }

#pragma unroll
    for (int i = 0; i < 4; ++i)
#pragma unroll
        for (int j = 0; j < 4; ++j)
#pragma unroll
            for (int r = 0; r < 4; ++r) {
                int gm = RM + wr + i * 16 + kg * 4 + r;
                int gn = CN + wc + j * 16 + r15;
                O[(size_t)gm * CC + gn] = acc[i][j][r];
            }
}

// -------------------------------------------------------------- launch -----
extern "C" void kernel_launch(void* const* d_in, const int* in_sizes, int n_in,
                              void* d_out, int out_size, void* d_ws, size_t ws_size,
                              hipStream_t stream) {
    const float* x  = (const float*)d_in[0];
    const float* W1 = (const float*)d_in[1];
    const float* W2 = (const float*)d_in[2];
    float* out = (float*)d_out;

    float*    h = out;               // fp32 h in d_out (clobbered by GEMM2)
    _Float16* s = (_Float16*)d_ws;   // fp16 spikes, 32 MB

    dim3 g1(MTOT / 128, CC / 256);   // (256, 2) = 512 blocks = 2/CU exactly
    gemm1_chain5<<<g1, 256, 0, stream>>>(x, W1, h);

    lif_np<<<BNC / 4 / 256, 256, 0, stream>>>(h, s);

    dim3 g2(MTOT / 128, CC / 128);   // (256, 4)
    gemm2_f16<<<g2, 256, 0, stream>>>(s, W2, out);
}

// Round 13
// 239.690 us; speedup vs baseline: 1.5307x; 1.1706x over previous
//
#include <hip/hip_runtime.h>

// SpikeFFN: out = spike(LIF(x @ W1^T)) @ W2^T ; T=4 B=8 N=1024 C=512, fp32.
//
// HARD CONSTRAINT (r8): GEMM1 = single full-K ascending serial FMA chain per
// output in fp32 (np reference arithmetic); v_fma_f32 == CPU vfmadd.
// Tiling/load order free; per-output chain order is not.
//
// r9-r12 post-mortem: per-lane B reads keep the LDS pipe >= VALU time
// (6 b128 per 128 FMA + 2e7 conflict cyc). r13: remove B from LDS entirely:
// pre-transpose W1 -> Wt[k][o] (1MB), each WAVE owns 16 cols and loads its
// B-row per k as a wave-uniform 64B read (scalar-load/broadcast path, no
// LDS). A: lane reads its 4 rows as one contiguous b128 (conflict-free).
// Per wave-k: 1 b128 vs 64 FMA -> VALU-bound with 4x LDS headroom.
// Spikes stored as 1 byte (0x3C = high byte of fp16 1.0) so Wt+spikes fit
// in the proven 32MB of d_ws; GEMM2 staging expands byte->half via shift.

typedef _Float16 half8  __attribute__((ext_vector_type(8)));
typedef _Float16 half4v __attribute__((ext_vector_type(4)));
typedef float    f32x4  __attribute__((ext_vector_type(4)));
typedef float    f32x16 __attribute__((ext_vector_type(16)));
typedef unsigned short ushort8 __attribute__((ext_vector_type(8)));

constexpr int TT   = 4;
constexpr int BB   = 8;
constexpr int NN   = 1024;
constexpr int CC   = 512;                 // Cin == Cout
constexpr int MROW = BB * NN;             // 8192 rows per timestep
constexpr int MTOT = TT * MROW;           // 32768 rows total
constexpr int BNC  = MROW * CC;           // per-timestep elems
constexpr int LDK  = 40;                  // fp16 LDS stride (gemm2)
constexpr int LTA  = 260;                 // fp32 LDS row stride (256+4 pad)

// --------------------------- W1 -> Wt[k][o] transpose ----------------------
__global__ __launch_bounds__(256)
void transpose_w(const float* __restrict__ W, float* __restrict__ Wt) {
    __shared__ float T[64][65];
    const int tid = threadIdx.x;
    const int bo  = blockIdx.x * 64;   // o tile
    const int bk  = blockIdx.y * 64;   // k tile
#pragma unroll
    for (int j = 0; j < 16; ++j) {
        int id = tid + 256 * j;
        int r = id >> 6, c = id & 63;              // r: o, c: k
        T[r][c] = W[(size_t)(bo + r) * CC + bk + c];
    }
    __syncthreads();
#pragma unroll
    for (int j = 0; j < 16; ++j) {
        int id = tid + 256 * j;
        int r = id >> 6, c = id & 63;              // r: k, c: o
        Wt[(size_t)(bk + r) * CC + bo + c] = T[c][r];
    }
}

// ---------- GEMM1: single full-K ascending serial FMA chain (fp32) ---------
// 256x128 block tile, 512 threads (8 waves x 16 cols), 4x16 outputs/thread.
// A in dbuf LDS (contiguous-b128 lane reads); B wave-uniform from Wt.
__global__ __launch_bounds__(512, 4)
void gemm1_smem(const float* __restrict__ X, const float* __restrict__ Wt,
                float* __restrict__ H) {
#pragma clang fp contract(off)
    __shared__ float At[2][32][LTA];   // 66.5 KB

    const int tid  = threadIdx.x;
    const int lane = tid & 63;
    const int wid  = __builtin_amdgcn_readfirstlane(tid >> 6);  // 0..7, uniform
    const int RM   = blockIdx.x * 256;
    const int CN   = blockIdx.y * 128 + wid * 16;  // wave col base (uniform)
    const float* wcol = Wt + CN;                   // Wt[k][CN..CN+15]

    const int srow = tid >> 1;           // staging row 0..255
    const int sk16 = (tid & 1) * 16;     // staging k base (0 or 16)

    float acc[4][16] = {};               // ONE accumulator per output
    f32x4 rx[4];

    // prologue: stage tile 0
#pragma unroll
    for (int q = 0; q < 4; ++q)
        rx[q] = *(const f32x4*)&X[(size_t)(RM + srow) * CC + sk16 + q * 4];
#pragma unroll
    for (int q = 0; q < 4; ++q)
#pragma unroll
        for (int e = 0; e < 4; ++e)
            At[0][sk16 + q * 4 + e][srow] = rx[q][e];
    __syncthreads();

    for (int kt = 0; kt < 16; ++kt) {
        const int cur = kt & 1;
        // issue global loads for tile kt+1 (land under this tile's FMAs)
        if (kt < 15) {
            int kk = (kt + 1) * 32;
#pragma unroll
            for (int q = 0; q < 4; ++q)
                rx[q] = *(const f32x4*)&X[(size_t)(RM + srow) * CC + kk + sk16 + q * 4];
        }
        // FMA phase: strict ascending k; B via wave-uniform 64B loads
#pragma unroll 4
        for (int k = 0; k < 32; ++k) {
            f32x4 a = *(const f32x4*)&At[cur][k][lane * 4];
            f32x16 b = *(const f32x16*)&wcol[(size_t)(kt * 32 + k) * CC];
#pragma unroll
            for (int i = 0; i < 4; ++i)
#pragma unroll
                for (int j = 0; j < 16; ++j)
                    acc[i][j] = __builtin_fmaf(a[i], b[j], acc[i][j]);
        }
        // stage tile kt+1 into the other buffer, one barrier per tile
        if (kt < 15) {
#pragma unroll
            for (int q = 0; q < 4; ++q)
#pragma unroll
                for (int e = 0; e < 4; ++e)
                    At[cur ^ 1][sk16 + q * 4 + e][srow] = rx[q][e];
            __syncthreads();
        }
    }

#pragma unroll
    for (int i = 0; i < 4; ++i) {
        size_t base = (size_t)(RM + lane * 4 + i) * CC + CN;
#pragma unroll
        for (int q = 0; q < 4; ++q) {
            f32x4 o = {acc[i][q * 4], acc[i][q * 4 + 1],
                       acc[i][q * 4 + 2], acc[i][q * 4 + 3]};
            *(f32x4*)&H[base + q * 4] = o;
        }
    }
}

// ----------------------------- LIF (fp32, np-op-exact) ---------------------
// Spike byte: 0x3C (= high byte of fp16 1.0) or 0x00.
__global__ __launch_bounds__(256)
void lif_np(const float* __restrict__ H, unsigned char* __restrict__ S8) {
#pragma clang fp contract(off)
    int g = blockIdx.x * 256 + threadIdx.x;   // 0 .. BNC/4-1
    float v[4] = {0.f, 0.f, 0.f, 0.f};
#pragma unroll
    for (int t = 0; t < TT; ++t) {
        f32x4 h = *(const f32x4*)&H[(size_t)t * BNC + (size_t)g * 4];
        unsigned int pack = 0;
#pragma unroll
        for (int e = 0; e < 4; ++e) {
            float d  = h[e] - v[e];          // rounded sub (np: x - (v-0))
            float d2 = d * 0.5f;             // exact (np: /2.0)
            v[e] = v[e] + d2;                // rounded add
            bool sp = v[e] >= 1.0f;
            if (sp) { pack |= 0x3Cu << (8 * e); v[e] = 0.0f; }
        }
        *(unsigned int*)&S8[(size_t)t * BNC + (size_t)g * 4] = pack;
    }
}

// ---------------------------------------------------------------- GEMM2 ----
// O[m][p] = sum_o S[m][o] * W2[p][o]. fp16 MFMA; spikes exact in fp16.
__global__ __launch_bounds__(256)
void gemm2_f16(const unsigned char* __restrict__ S8, const float* __restrict__ W,
               float* __restrict__ O) {
    __shared__ _Float16 As[128][LDK], Bs[128][LDK];

    const int tid  = threadIdx.x;
    const int RM   = blockIdx.x * 128;
    const int CN   = blockIdx.y * 128;
    const int lane = tid & 63;
    const int wv   = tid >> 6;
    const int wr   = (wv >> 1) * 64;
    const int wc   = (wv & 1) * 64;
    const int r15  = lane & 15;
    const int kg   = lane >> 4;

    f32x4 acc[4][4] = {};

    for (int k0 = 0; k0 < CC; k0 += 32) {
        __syncthreads();
#pragma unroll
        for (int j = 0; j < 2; ++j) {
            int id  = tid + 256 * j;
            int row = id >> 2;
            int c8  = (id & 3) * 8;
            unsigned long long v =
                *(const unsigned long long*)&S8[(size_t)(RM + row) * CC + k0 + c8];
            ushort8 u;
#pragma unroll
            for (int e = 0; e < 8; ++e)
                u[e] = (unsigned short)(((v >> (8 * e)) & 0xFFull) << 8);
            *(ushort8*)&As[row][c8] = u;
        }
#pragma unroll
        for (int j = 0; j < 4; ++j) {
            int id  = tid + 256 * j;
            int row = id >> 3;
            int c4  = (id & 7) * 4;
            f32x4 v = *(const f32x4*)&W[(size_t)(CN + row) * CC + k0 + c4];
            half4v hv;
#pragma unroll
            for (int e = 0; e < 4; ++e) hv[e] = (_Float16)v[e];
            *(half4v*)&Bs[row][c4] = hv;
        }
        __syncthreads();

        half8 a[4], b[4];
#pragma unroll
        for (int i = 0; i < 4; ++i) {
            a[i] = *(const half8*)&As[wr + i * 16 + r15][kg * 8];
            b[i] = *(const half8*)&Bs[wc + i * 16 + r15][kg * 8];
        }
#pragma unroll
        for (int i = 0; i < 4; ++i)
#pragma unroll
            for (int j = 0; j < 4; ++j)
                acc[i][j] = __builtin_amdgcn_mfma_f32_16x16x32_f16(a[i], b[j], acc[i][j], 0, 0, 0);
    }

#pragma unroll
    for (int i = 0; i < 4; ++i)
#pragma unroll
        for (int j = 0; j < 4; ++j)
#pragma unroll
            for (int r = 0; r < 4; ++r) {
                int gm = RM + wr + i * 16 + kg * 4 + r;
                int gn = CN + wc + j * 16 + r15;
                O[(size_t)gm * CC + gn] = acc[i][j][r];
            }
}

// -------------------------------------------------------------- launch -----
extern "C" void kernel_launch(void* const* d_in, const int* in_sizes, int n_in,
                              void* d_out, int out_size, void* d_ws, size_t ws_size,
                              hipStream_t stream) {
    const float* x  = (const float*)d_in[0];
    const float* W1 = (const float*)d_in[1];
    const float* W2 = (const float*)d_in[2];
    float* out = (float*)d_out;

    float*         h  = out;                                   // fp32 h in d_out
    unsigned char* s8 = (unsigned char*)d_ws;                  // spikes, 16 MB
    float*         wt = (float*)((char*)d_ws + (size_t)BNC);   // Wt, 1 MB @ +16MB

    dim3 gt(CC / 64, CC / 64);       // (8, 8)
    transpose_w<<<gt, 256, 0, stream>>>(W1, wt);

    dim3 g1(MTOT / 256, CC / 128);   // (128, 4) = 512 blocks = 2/CU
    gemm1_smem<<<g1, 512, 0, stream>>>(x, wt, h);

    lif_np<<<BNC / 4 / 256, 256, 0, stream>>>(h, s8);

    dim3 g2(MTOT / 128, CC / 128);   // (256, 4)
    gemm2_f16<<<g2, 256, 0, stream>>>(s8, W2, out);
}